// Round 5
// baseline (4855.133 us; speedup 1.0000x reference)
//
#include <hip/hip_runtime.h>
#include <hip/hip_cooperative_groups.h>
#include <math.h>

namespace cg = cooperative_groups;

// Instant-NGP hash grid encoder, MI355X. Round 5.
//
// Round-4 post-mortem:
//  - gather: FETCH 1.66 GB vs ~0.41 GB ideal; occupancy 57% -> blocks NOT
//    phase-locked across the grid (per-block __syncthreads can't stop
//    inter-block drift). Fix: cooperative launch + grid.sync() per level ->
//    each XCD L2 holds exactly one 4 MB level slice at a time.
//  - transpose: ~360 us (6x streaming floor). Cause: nontemporal f32x4
//    stores at 128 B lane stride = partial-line nt writes -> no L2 merge,
//    write amplification. Fix: temporal stores (same-thread back-to-back
//    16 B stores complete full 64 B lines in L2). nt is kept ONLY where
//    stores are wave-contiguous per instruction (gather -> out_t).

#define LEVELS 16
#define LOG2_T 19
#define TMASK ((1u << LOG2_T) - 1u)

typedef float f32x2 __attribute__((ext_vector_type(2)));
typedef float f32x4 __attribute__((ext_vector_type(4)));

struct ResArgs { float r[LEVELS]; };

#define GATHER_BLOCKS 2048u   // 8 blocks/CU x 256 CU; x2 pts/thread = 2^20

__device__ __forceinline__ f32x2 encode_one(
    const f32x2* __restrict__ tbl, float rf,
    float x0, float x1, float x2)
{
    // Same fp32 op chain as the reference.
    const float sx = x0 * rf, sy = x1 * rf, sz = x2 * rf;
    const float px = floorf(sx), py = floorf(sy), pz = floorf(sz);
    const float fx = sx - px, fy = sy - py, fz = sz - pz;
    const unsigned ix = (unsigned)px, iy = (unsigned)py, iz = (unsigned)pz;

    const unsigned hx0 = ix;
    const unsigned hx1 = ix + 1u;
    const unsigned hy0 = iy * 2654435761u;
    const unsigned hy1 = hy0 + 2654435761u;
    const unsigned hz0 = iz * 805459861u;
    const unsigned hz1 = hz0 + 805459861u;

    const unsigned i000 = (hx0 ^ hy0 ^ hz0) & TMASK;
    const unsigned i100 = (hx1 ^ hy0 ^ hz0) & TMASK;
    const unsigned i010 = (hx0 ^ hy1 ^ hz0) & TMASK;
    const unsigned i110 = (hx1 ^ hy1 ^ hz0) & TMASK;
    const unsigned i001 = (hx0 ^ hy0 ^ hz1) & TMASK;
    const unsigned i101 = (hx1 ^ hy0 ^ hz1) & TMASK;
    const unsigned i011 = (hx0 ^ hy1 ^ hz1) & TMASK;
    const unsigned i111 = (hx1 ^ hy1 ^ hz1) & TMASK;

    const f32x2 c000 = tbl[i000];
    const f32x2 c100 = tbl[i100];
    const f32x2 c010 = tbl[i010];
    const f32x2 c110 = tbl[i110];
    const f32x2 c001 = tbl[i001];
    const f32x2 c101 = tbl[i101];
    const f32x2 c011 = tbl[i011];
    const f32x2 c111 = tbl[i111];

    const float wx1 = fx, wx0 = 1.0f - fx;
    const float wy1 = fy, wy0 = 1.0f - fy;
    const float wz1 = fz, wz0 = 1.0f - fz;
    const float w00 = wy0 * wz0;
    const float w10 = wy1 * wz0;
    const float w01 = wy0 * wz1;
    const float w11 = wy1 * wz1;

    float w, a0, a1;
    w = wx0 * w00; a0 = w * c000.x;          a1 = w * c000.y;
    w = wx1 * w00; a0 = fmaf(w, c100.x, a0); a1 = fmaf(w, c100.y, a1);
    w = wx0 * w10; a0 = fmaf(w, c010.x, a0); a1 = fmaf(w, c010.y, a1);
    w = wx1 * w10; a0 = fmaf(w, c110.x, a0); a1 = fmaf(w, c110.y, a1);
    w = wx0 * w01; a0 = fmaf(w, c001.x, a0); a1 = fmaf(w, c001.y, a1);
    w = wx1 * w01; a0 = fmaf(w, c101.x, a0); a1 = fmaf(w, c101.y, a1);
    w = wx0 * w11; a0 = fmaf(w, c011.x, a0); a1 = fmaf(w, c011.y, a1);
    w = wx1 * w11; a0 = fmaf(w, c111.x, a0); a1 = fmaf(w, c111.y, a1);

    f32x2 o; o.x = a0; o.y = a1;
    return o;
}

// ---- Cooperative phase-locked gather: grid.sync() between levels --------
__global__ __launch_bounds__(256, 8) void ngp_gather_coop(
    const float* __restrict__ x,
    const float* __restrict__ table,
    f32x2* __restrict__ out_t,     // [LEVELS][n] scratch
    ResArgs res,
    unsigned n)
{
    cg::grid_group grid = cg::this_grid();
    const unsigned tid = blockIdx.x * 256u + threadIdx.x;
    const unsigned stride = GATHER_BLOCKS * 256u;   // 524288
    const unsigned p0 = tid;
    const unsigned p1 = tid + stride;
    const bool v0 = p0 < n, v1 = p1 < n;

    // x read exactly once into registers; nt loads keep the 12 MB x stream
    // from polluting the L2 slice residency.
    float a0 = 0.f, a1 = 0.f, a2 = 0.f, b0 = 0.f, b1 = 0.f, b2 = 0.f;
    if (v0) {
        a0 = __builtin_nontemporal_load(&x[3u*p0]);
        a1 = __builtin_nontemporal_load(&x[3u*p0+1u]);
        a2 = __builtin_nontemporal_load(&x[3u*p0+2u]);
    }
    if (v1) {
        b0 = __builtin_nontemporal_load(&x[3u*p1]);
        b1 = __builtin_nontemporal_load(&x[3u*p1+1u]);
        b2 = __builtin_nontemporal_load(&x[3u*p1+2u]);
    }

    #pragma unroll 1
    for (int l = 0; l < LEVELS; ++l) {
        const float rf = res.r[l];
        const f32x2* __restrict__ tbl =
            (const f32x2*)table + ((size_t)l << LOG2_T);
        if (v0) {
            f32x2 o = encode_one(tbl, rf, a0, a1, a2);
            // wave-contiguous per instruction (8 B x 64 lanes) -> nt OK
            __builtin_nontemporal_store(o, &out_t[(size_t)l * n + p0]);
        }
        if (v1) {
            f32x2 o = encode_one(tbl, rf, b0, b1, b2);
            __builtin_nontemporal_store(o, &out_t[(size_t)l * n + p1]);
        }
        if (l != LEVELS - 1) grid.sync();   // hard phase boundary
    }
}

// ---- Fallback gather (round-4, block-local phasing only) ---------------
__global__ __launch_bounds__(256, 8) void ngp_gather_phased(
    const float* __restrict__ x,
    const float* __restrict__ table,
    f32x2* __restrict__ out_t,
    ResArgs res,
    unsigned n)
{
    const unsigned tid = blockIdx.x * 256u + threadIdx.x;
    const unsigned stride = GATHER_BLOCKS * 256u;
    const unsigned p0 = tid;
    const unsigned p1 = tid + stride;
    const bool v0 = p0 < n, v1 = p1 < n;

    float a0 = 0.f, a1 = 0.f, a2 = 0.f, b0 = 0.f, b1 = 0.f, b2 = 0.f;
    if (v0) { a0 = x[3u*p0]; a1 = x[3u*p0+1u]; a2 = x[3u*p0+2u]; }
    if (v1) { b0 = x[3u*p1]; b1 = x[3u*p1+1u]; b2 = x[3u*p1+2u]; }

    #pragma unroll 1
    for (int l = 0; l < LEVELS; ++l) {
        const float rf = res.r[l];
        const f32x2* __restrict__ tbl =
            (const f32x2*)table + ((size_t)l << LOG2_T);
        if (v0) {
            f32x2 o = encode_one(tbl, rf, a0, a1, a2);
            __builtin_nontemporal_store(o, &out_t[(size_t)l * n + p0]);
        }
        if (v1) {
            f32x2 o = encode_one(tbl, rf, b0, b1, b2);
            __builtin_nontemporal_store(o, &out_t[(size_t)l * n + p1]);
        }
        __syncthreads();
    }
}

// ---- Streaming transpose [L][N] -> [N][L]. TEMPORAL stores so L2 merges
// the per-thread 16 B segments into full lines (round-4 lesson). ----------
__global__ __launch_bounds__(256) void ngp_transpose(
    const f32x2* __restrict__ out_t,
    f32x4* __restrict__ out,       // [n][8] f32x4
    unsigned n)
{
    const unsigned p = blockIdx.x * 256u + threadIdx.x;
    if (p >= n) return;
    f32x2 v[LEVELS];
    #pragma unroll
    for (int l = 0; l < LEVELS; ++l)
        v[l] = out_t[(size_t)l * n + p];          // coalesced per level
    #pragma unroll
    for (int j = 0; j < LEVELS / 2; ++j) {
        f32x4 q; q.x = v[2*j].x; q.y = v[2*j].y; q.z = v[2*j+1].x; q.w = v[2*j+1].y;
        out[(size_t)p * (LEVELS/2) + j] = q;      // temporal: L2 merges
    }
}

// ---- Last-resort direct kernel (round-3 proven, 872 us) -----------------
__global__ __launch_bounds__(256) void ngp_encode_direct(
    const float* __restrict__ x,
    const float* __restrict__ table,
    f32x2* __restrict__ out,
    ResArgs res,
    unsigned n_points)
{
    const unsigned t = blockIdx.x * 256u + threadIdx.x;
    const unsigned level = t & (LEVELS - 1u);
    const unsigned p = t >> 4;
    if (p >= n_points) return;
    const float x0 = x[3u*p], x1 = x[3u*p+1u], x2 = x[3u*p+2u];
    const f32x2* __restrict__ tbl =
        (const f32x2*)table + ((size_t)level << LOG2_T);
    f32x2 o = encode_one(tbl, res.r[level], x0, x1, x2);
    __builtin_nontemporal_store(o, &out[t]);
}

extern "C" void kernel_launch(void* const* d_in, const int* in_sizes, int n_in,
                              void* d_out, int out_size, void* d_ws, size_t ws_size,
                              hipStream_t stream) {
    const float* x     = (const float*)d_in[0];
    const float* table = (const float*)d_in[1];
    const unsigned n_points = (unsigned)(in_sizes[0] / 3);

    // numpy RES replication (same host libm).
    ResArgs res;
    const double scale = exp((log(512.0) - log(16.0)) / 15.0);
    for (int l = 0; l < LEVELS; ++l) {
        res.r[l] = (float)floor(16.0 * pow(scale, (double)l));
    }

    const size_t scratch_needed = (size_t)LEVELS * n_points * sizeof(f32x2);
    const bool fits = (ws_size >= scratch_needed) &&
                      (n_points <= 2u * GATHER_BLOCKS * 256u);

    if (fits) {
        f32x2* out_t = (f32x2*)d_ws;
        unsigned np = n_points;
        void* args[] = { (void*)&x, (void*)&table, (void*)&out_t,
                         (void*)&res, (void*)&np };
        hipError_t e = hipLaunchCooperativeKernel(
            ngp_gather_coop, dim3(GATHER_BLOCKS), dim3(256), args, 0, stream);
        if (e != hipSuccess) {
            // harness/capture rejected coop launch -> block-phased fallback
            ngp_gather_phased<<<dim3(GATHER_BLOCKS), dim3(256), 0, stream>>>(
                x, table, out_t, res, n_points);
        }
        const unsigned tblk = (n_points + 255u) / 256u;
        ngp_transpose<<<dim3(tblk), dim3(256), 0, stream>>>(
            out_t, (f32x4*)d_out, n_points);
    } else {
        const unsigned total = n_points * LEVELS;
        const unsigned nblk = (total + 255u) / 256u;
        ngp_encode_direct<<<dim3(nblk), dim3(256), 0, stream>>>(
            x, table, (f32x2*)d_out, res, n_points);
    }
}

// Round 6
// 638.196 us; speedup vs baseline: 7.6076x; 7.6076x over previous
//
#include <hip/hip_runtime.h>
#include <math.h>

// Instant-NGP hash grid encoder, MI355X. Round 6: per-level dispatches.
//
// Round-5 post-mortem: coop grid.sync() gave IDEAL traffic (FETCH 185 MB
// vs 3.0 GB baseline -- phase coherence proven) but the ROCm grid barrier
// is a global-atomic spin: ~300 us x 15 syncs = 4.9 ms, VALUBusy 0.7%.
// Lesson: on MI355X never use grid.sync() as an inner-loop phase barrier.
// This round: same level-phased schedule, but the phase boundary is the
// stream-ordered kernel boundary (16 per-level launches, ~us each in a
// captured graph). Transpose rebuilt with an LDS tile so ALL global
// accesses are per-instruction wave-contiguous (no reliance on L2 write
// merging; round-4 lesson).

#define LEVELS 16
#define LOG2_T 19
#define TMASK ((1u << LOG2_T) - 1u)

typedef float f32x2 __attribute__((ext_vector_type(2)));
typedef float f32x4 __attribute__((ext_vector_type(4)));

struct ResArgs { float r[LEVELS]; };

__device__ __forceinline__ f32x2 encode_one(
    const f32x2* __restrict__ tbl, float rf,
    float x0, float x1, float x2)
{
    // Same fp32 op chain as the reference.
    const float sx = x0 * rf, sy = x1 * rf, sz = x2 * rf;
    const float px = floorf(sx), py = floorf(sy), pz = floorf(sz);
    const float fx = sx - px, fy = sy - py, fz = sz - pz;
    const unsigned ix = (unsigned)px, iy = (unsigned)py, iz = (unsigned)pz;

    const unsigned hx0 = ix;
    const unsigned hx1 = ix + 1u;
    const unsigned hy0 = iy * 2654435761u;
    const unsigned hy1 = hy0 + 2654435761u;
    const unsigned hz0 = iz * 805459861u;
    const unsigned hz1 = hz0 + 805459861u;

    const unsigned i000 = (hx0 ^ hy0 ^ hz0) & TMASK;
    const unsigned i100 = (hx1 ^ hy0 ^ hz0) & TMASK;
    const unsigned i010 = (hx0 ^ hy1 ^ hz0) & TMASK;
    const unsigned i110 = (hx1 ^ hy1 ^ hz0) & TMASK;
    const unsigned i001 = (hx0 ^ hy0 ^ hz1) & TMASK;
    const unsigned i101 = (hx1 ^ hy0 ^ hz1) & TMASK;
    const unsigned i011 = (hx0 ^ hy1 ^ hz1) & TMASK;
    const unsigned i111 = (hx1 ^ hy1 ^ hz1) & TMASK;

    const f32x2 c000 = tbl[i000];
    const f32x2 c100 = tbl[i100];
    const f32x2 c010 = tbl[i010];
    const f32x2 c110 = tbl[i110];
    const f32x2 c001 = tbl[i001];
    const f32x2 c101 = tbl[i101];
    const f32x2 c011 = tbl[i011];
    const f32x2 c111 = tbl[i111];

    const float wx1 = fx, wx0 = 1.0f - fx;
    const float wy1 = fy, wy0 = 1.0f - fy;
    const float wz1 = fz, wz0 = 1.0f - fz;
    const float w00 = wy0 * wz0;
    const float w10 = wy1 * wz0;
    const float w01 = wy0 * wz1;
    const float w11 = wy1 * wz1;

    float w, a0, a1;
    w = wx0 * w00; a0 = w * c000.x;          a1 = w * c000.y;
    w = wx1 * w00; a0 = fmaf(w, c100.x, a0); a1 = fmaf(w, c100.y, a1);
    w = wx0 * w10; a0 = fmaf(w, c010.x, a0); a1 = fmaf(w, c010.y, a1);
    w = wx1 * w10; a0 = fmaf(w, c110.x, a0); a1 = fmaf(w, c110.y, a1);
    w = wx0 * w01; a0 = fmaf(w, c001.x, a0); a1 = fmaf(w, c001.y, a1);
    w = wx1 * w01; a0 = fmaf(w, c101.x, a0); a1 = fmaf(w, c101.y, a1);
    w = wx0 * w11; a0 = fmaf(w, c011.x, a0); a1 = fmaf(w, c011.y, a1);
    w = wx1 * w11; a0 = fmaf(w, c111.x, a0); a1 = fmaf(w, c111.y, a1);

    f32x2 o; o.x = a0; o.y = a1;
    return o;
}

// ---- One level per dispatch: stream order = hard phase boundary ---------
__global__ __launch_bounds__(256) void ngp_gather_level(
    const float* __restrict__ x,
    const float* __restrict__ table,
    f32x2* __restrict__ out_t,     // [LEVELS][n] scratch
    float rf, int level, unsigned n)
{
    const unsigned p = blockIdx.x * 256u + threadIdx.x;
    if (p >= n) return;
    // nt loads: x must not evict the 4 MB table slice from the XCD L2.
    const float x0 = __builtin_nontemporal_load(&x[3u*p]);
    const float x1 = __builtin_nontemporal_load(&x[3u*p+1u]);
    const float x2 = __builtin_nontemporal_load(&x[3u*p+2u]);
    const f32x2* __restrict__ tbl =
        (const f32x2*)table + ((size_t)level << LOG2_T);
    f32x2 o = encode_one(tbl, rf, x0, x1, x2);
    // wave-contiguous 512 B per instruction -> nt safe & desirable.
    __builtin_nontemporal_store(o, &out_t[(size_t)level * n + p]);
}

// ---- LDS tile transpose [L][N] -> [N][L]: both sides per-instruction
// wave-contiguous. LDS row padded 16->17 f32x2 => 2-way banking (free). ---
__global__ __launch_bounds__(256) void ngp_transpose_lds(
    const f32x2* __restrict__ out_t,
    f32x4* __restrict__ out,       // [n*8] f32x4
    unsigned n)
{
    __shared__ f32x2 lds[256][LEVELS + 1];
    const unsigned t = threadIdx.x;
    const unsigned p0 = blockIdx.x * 256u;   // n % 256 == 0 (checked on host)

    #pragma unroll
    for (int l = 0; l < LEVELS; ++l)
        lds[t][l] = out_t[(size_t)l * n + p0 + t];   // 2 KB/wave contiguous
    __syncthreads();

    #pragma unroll
    for (int j = 0; j < 8; ++j) {
        const unsigned g = (unsigned)j * 256u + t;   // f32x4 index in tile
        const unsigned p = g >> 3, q = g & 7u;
        const f32x2 a = lds[p][2u*q];
        const f32x2 b = lds[p][2u*q + 1u];
        f32x4 v; v.x = a.x; v.y = a.y; v.z = b.x; v.w = b.y;
        // 1 KB/wave contiguous per instruction -> nt write-once stream.
        __builtin_nontemporal_store(v, &out[(size_t)p0 * 8u + g]);
    }
}

// ---- Fallback (round-3 proven, 872 us): direct point-major --------------
__global__ __launch_bounds__(256) void ngp_encode_direct(
    const float* __restrict__ x,
    const float* __restrict__ table,
    f32x2* __restrict__ out,
    ResArgs res,
    unsigned n_points)
{
    const unsigned t = blockIdx.x * 256u + threadIdx.x;
    const unsigned level = t & (LEVELS - 1u);
    const unsigned p = t >> 4;
    if (p >= n_points) return;
    const float x0 = x[3u*p], x1 = x[3u*p+1u], x2 = x[3u*p+2u];
    const f32x2* __restrict__ tbl =
        (const f32x2*)table + ((size_t)level << LOG2_T);
    f32x2 o = encode_one(tbl, res.r[level], x0, x1, x2);
    __builtin_nontemporal_store(o, &out[t]);
}

extern "C" void kernel_launch(void* const* d_in, const int* in_sizes, int n_in,
                              void* d_out, int out_size, void* d_ws, size_t ws_size,
                              hipStream_t stream) {
    const float* x     = (const float*)d_in[0];
    const float* table = (const float*)d_in[1];
    const unsigned n_points = (unsigned)(in_sizes[0] / 3);

    // numpy RES replication (same host libm).
    ResArgs res;
    const double scale = exp((log(512.0) - log(16.0)) / 15.0);
    for (int l = 0; l < LEVELS; ++l) {
        res.r[l] = (float)floor(16.0 * pow(scale, (double)l));
    }

    const size_t scratch_needed = (size_t)LEVELS * n_points * sizeof(f32x2);
    const bool fits = (ws_size >= scratch_needed) && (n_points % 256u == 0u);

    if (fits) {
        f32x2* out_t = (f32x2*)d_ws;
        const unsigned nblk = n_points / 256u;
        for (int l = 0; l < LEVELS; ++l) {
            ngp_gather_level<<<dim3(nblk), dim3(256), 0, stream>>>(
                x, table, out_t, res.r[l], l, n_points);
        }
        ngp_transpose_lds<<<dim3(nblk), dim3(256), 0, stream>>>(
            out_t, (f32x4*)d_out, n_points);
    } else {
        const unsigned total = n_points * LEVELS;
        const unsigned nblk = (total + 255u) / 256u;
        ngp_encode_direct<<<dim3(nblk), dim3(256), 0, stream>>>(
            x, table, (f32x2*)d_out, res, n_points);
    }
}